// Round 7
// baseline (148.770 us; speedup 1.0000x reference)
//
#include <hip/hip_runtime.h>

// AttentionConv on MI355X (gfx950) — fully fused, all-channels-per-block.
// wprep: W[576][192] -> bf16 hi/lo, fragment-major (lane-coalesced) in d_ws.
// fused: per 64x64-px tile of one b (ALL 3 channels):
//   1) stage 80x80 halo x-region (3 input ch serially) -> LDS bf16 hi/lo
//   2) M=128(pad 100 patches) x N=576(q,k,v x 3c x 64 dl) x K=192 bf16x3 MFMA
//   3) per output channel: w=(k+bk)(v+bv) -> LDS, stencil from acc-q -> out
// OOB halo patches: x=0 -> k,v = bias -> w = bk*bv automatically.

#define HW 512

typedef __attribute__((ext_vector_type(8))) short bf16x8;
typedef __attribute__((ext_vector_type(4))) float f32x4;

static __device__ __forceinline__ unsigned short bf16_rne(float f) {
    unsigned u = __builtin_bit_cast(unsigned, f);
    u += 0x7FFFu + ((u >> 16) & 1u);
    return (unsigned short)(u >> 16);
}
static __device__ __forceinline__ float bf16f(unsigned short h) {
    unsigned u = ((unsigned)h) << 16;
    return __builtin_bit_cast(float, u);
}

// ---------- prep: W -> fragment-major bf16 hi/lo ----------
// Ws[kt][half][kg 0..7][e 0..575][8 ushorts]; entry = W[e][kt*64 + kg*8 .. +7]
__global__ void __launch_bounds__(256) wprep_kernel(const float* __restrict__ W,
                                                    unsigned short* __restrict__ Ws)
{
    int gid = blockIdx.x * 256 + threadIdx.x;      // 13824 = 54*256 exact
    int e  = gid % 576;
    int t  = gid / 576;                            // 0..23
    int kg = t & 7;
    int kt = t >> 3;
    const float* src = W + (size_t)e*192 + kt*64 + kg*8;
    float4 a = ((const float4*)src)[0], b = ((const float4*)src)[1];
    float v[8] = {a.x, a.y, a.z, a.w, b.x, b.y, b.z, b.w};
    unsigned short h[8], lo[8];
    #pragma unroll
    for (int u = 0; u < 8; ++u) {
        h[u]  = bf16_rne(v[u]);
        lo[u] = bf16_rne(v[u] - bf16f(h[u]));
    }
    uint4 hp, lp;
    hp.x = (unsigned)h[0] | ((unsigned)h[1] << 16);
    hp.y = (unsigned)h[2] | ((unsigned)h[3] << 16);
    hp.z = (unsigned)h[4] | ((unsigned)h[5] << 16);
    hp.w = (unsigned)h[6] | ((unsigned)h[7] << 16);
    lp.x = (unsigned)lo[0] | ((unsigned)lo[1] << 16);
    lp.y = (unsigned)lo[2] | ((unsigned)lo[3] << 16);
    lp.z = (unsigned)lo[4] | ((unsigned)lo[5] << 16);
    lp.w = (unsigned)lo[6] | ((unsigned)lo[7] << 16);
    size_t oh = ((((size_t)kt*2 + 0)*8 + kg)*576 + e) * 8;
    size_t ol = ((((size_t)kt*2 + 1)*8 + kg)*576 + e) * 8;
    *(uint4*)(Ws + oh) = hp;
    *(uint4*)(Ws + ol) = lp;
}

// ---------- fused kernel ----------
__global__ void __launch_bounds__(512, 2) fused_kernel(
    const float* __restrict__ x,
    const unsigned short* __restrict__ Ws,
    const float* __restrict__ bqkv,
    float* __restrict__ out)
{
    __shared__ char smem[32768];
    unsigned short* Ah = (unsigned short*)smem;            // [128][64] bf16, swizzled
    unsigned short* Al = (unsigned short*)(smem + 16384);
    float* w_lds = (float*)smem;                           // [100][68] (post-GEMM)

    const int tid = threadIdx.x;
    const int bid = blockIdx.x;
    const int tx = bid & 7;
    const int ty = (bid >> 3) & 7;
    const int b  = bid >> 6;

    const int wv = tid >> 6;          // wave 0..7
    const int l  = tid & 63;
    const int lr = l & 15;
    const int lk = l >> 4;
    const int wm = wv & 1;            // M half: patch rows wm*64..+63
    const int wn = wv >> 1;           // dl quarter: wn*16..+15

    // acc[mf][nf]: nf = slot*3 + cc  (slot 0=q,1=k,2=v; cc = output channel)
    f32x4 acc[4][9];
    #pragma unroll
    for (int mf = 0; mf < 4; ++mf)
        #pragma unroll
        for (int nf = 0; nf < 9; ++nf)
            #pragma unroll
            for (int r = 0; r < 4; ++r) acc[mf][nf][r] = 0.f;

    const int gy0 = ty*64 - 8, gx0 = tx*64 - 8;

    for (int kt = 0; kt < 3; ++kt) {
        // ---- stage 80x80 x-region -> Ah/Al (bf16 hi/lo, XOR-swizzled) ----
        const float* xp = x + (size_t)(b*3 + kt) * HW * HW;
        #pragma unroll
        for (int it = 0; it < 4; ++it) {
            int f = tid + it*512;
            if (f < 1600) {                        // 80 rows x 20 float4
                int r  = f / 20;
                int c4 = f - r*20;
                int gy = gy0 + r;
                int gx = gx0 + c4*4;
                float4 v = make_float4(0.f, 0.f, 0.f, 0.f);
                if ((unsigned)gy < 512u && (unsigned)gx < 512u)
                    v = *(const float4*)(xp + (size_t)gy*HW + gx);
                int p  = (r >> 3)*10 + (c4 >> 1);          // halo patch 0..99
                int kk = (r & 7)*8 + (c4 & 1)*4;           // pi*8 + pj0
                unsigned short h0 = bf16_rne(v.x), h1 = bf16_rne(v.y),
                               h2 = bf16_rne(v.z), h3 = bf16_rne(v.w);
                unsigned short q0 = bf16_rne(v.x - bf16f(h0)), q1 = bf16_rne(v.y - bf16f(h1)),
                               q2 = bf16_rne(v.z - bf16f(h2)), q3 = bf16_rne(v.w - bf16f(h3));
                int byte = (p*128 + kk*2) ^ ((p & 7) << 4);
                *(uint2*)((char*)Ah + byte) = make_uint2((unsigned)h0 | ((unsigned)h1 << 16),
                                                         (unsigned)h2 | ((unsigned)h3 << 16));
                *(uint2*)((char*)Al + byte) = make_uint2((unsigned)q0 | ((unsigned)q1 << 16),
                                                         (unsigned)q2 | ((unsigned)q3 << 16));
            }
        }
        __syncthreads();

        // ---- GEMM over this kt (K=64, two 32-steps), N = all 576 ----
        const unsigned short* Wk = Ws + (size_t)kt * 2 * 8 * 576 * 8;
        #pragma unroll
        for (int ks = 0; ks < 2; ++ks) {
            bf16x8 ah[4], al[4];
            #pragma unroll
            for (int mf = 0; mf < 4; ++mf) {
                int row = wm*64 + mf*16 + lr;
                int byte = (row*128 + ks*64 + lk*16) ^ ((row & 7) << 4);
                ah[mf] = *(const bf16x8*)((const char*)Ah + byte);
                al[mf] = *(const bf16x8*)((const char*)Al + byte);
            }
            int kg = ks*4 + lk;
            const unsigned short* Bh = Wk + (size_t)kg * 576 * 8;
            const unsigned short* Bl = Wk + (size_t)(8 + kg) * 576 * 8;
            #pragma unroll
            for (int nf = 0; nf < 9; ++nf) {
                int slot = nf / 3, cc = nf % 3;
                int e = slot*192 + cc*64 + wn*16 + lr;
                bf16x8 bh = *(const bf16x8*)(Bh + (size_t)e * 8);
                bf16x8 bl = *(const bf16x8*)(Bl + (size_t)e * 8);
                #pragma unroll
                for (int mf = 0; mf < 4; ++mf) {
                    acc[mf][nf] = __builtin_amdgcn_mfma_f32_16x16x32_bf16(al[mf], bh, acc[mf][nf], 0, 0, 0);
                    acc[mf][nf] = __builtin_amdgcn_mfma_f32_16x16x32_bf16(ah[mf], bl, acc[mf][nf], 0, 0, 0);
                    acc[mf][nf] = __builtin_amdgcn_mfma_f32_16x16x32_bf16(ah[mf], bh, acc[mf][nf], 0, 0, 0);
                }
            }
        }
        __syncthreads();
    }

    // ---- epilogue: per-lane constants ----
    const int dl  = wn*16 + lr;        // D col = lane&15  [m89]
    const int pi_ = dl >> 3, pj_ = dl & 7;
    const float fr0 = __expf((float)(pi_ - 7) * 0.25f);
    const float fr2 = __expf((float)(-pi_) * 0.25f);
    const float fa  = __expf((float)(pj_ - 7) * 0.25f);
    const float fb  = __expf((float)(-pj_) * 0.25f);
    float bqc[3], bkc[3], bvc[3];
    #pragma unroll
    for (int cc = 0; cc < 3; ++cc) {
        bqc[cc] = bqkv[      cc*64 + dl];
        bkc[cc] = bqkv[192 + cc*64 + dl];
        bvc[cc] = bqkv[384 + cc*64 + dl];
    }

    // ---- per output channel: w -> LDS, stencil from register-q ----
    #pragma unroll
    for (int cc = 0; cc < 3; ++cc) {
        #pragma unroll
        for (int mf = 0; mf < 4; ++mf)
            #pragma unroll
            for (int ri = 0; ri < 4; ++ri) {
                int p = wm*64 + mf*16 + lk*4 + ri;      // D row = (l>>4)*4 + reg
                if (p < 100)
                    w_lds[p*68 + dl] = (acc[mf][3 + cc][ri] + bkc[cc]) *
                                       (acc[mf][6 + cc][ri] + bvc[cc]);
            }
        __syncthreads();

        #pragma unroll
        for (int mf = 0; mf < 4; ++mf)
            #pragma unroll
            for (int ri = 0; ri < 4; ++ri) {
                int p  = wm*64 + mf*16 + lk*4 + ri;
                int Pr = p / 10, Pc = p - Pr*10;
                if (Pr >= 1 && Pr <= 8 && Pc >= 1 && Pc <= 8 && p < 100) {
                    const float* bse = w_lds + p*68 + dl;
                    float s;
                    s  = fr0 * (fa*bse[-11*68] + bse[-10*68] + fb*bse[-9*68]);
                    s +=       (fa*bse[ -1*68] + bse[  0   ] + fb*bse[ 1*68]);
                    s += fr2 * (fa*bse[  9*68] + bse[ 10*68] + fb*bse[11*68]);
                    float qv = acc[mf][cc][ri] + bqc[cc];
                    int y  = ty*64 + (Pr - 1)*8 + pi_;
                    int xg = tx*64 + (Pc - 1)*8 + pj_;
                    out[((size_t)(b*3 + cc)*HW + y)*HW + xg] = qv * s;
                }
            }
        __syncthreads();
    }
}

extern "C" void kernel_launch(void* const* d_in, const int* in_sizes, int n_in,
                              void* d_out, int out_size, void* d_ws, size_t ws_size,
                              hipStream_t stream)
{
    const float* x  = (const float*)d_in[0];   // [8][3][512][512]
    const float* W  = (const float*)d_in[1];   // [576][192]
    const float* bq = (const float*)d_in[2];   // [576]
    unsigned short* Ws = (unsigned short*)d_ws; // 442 KB W-split

    wprep_kernel<<<54, 256, 0, stream>>>(W, Ws);
    fused_kernel<<<512, 512, 0, stream>>>(x, Ws, bq, (float*)d_out);
}

// Round 10
// 122.473 us; speedup vs baseline: 1.2147x; 1.2147x over previous
//
#include <hip/hip_runtime.h>

// AttentionConv on MI355X (gfx950) — split design (R5 structure, verified).
// wprep: W -> bf16 hi/lo, fragment-major (lane-coalesced).
// qkv  : per-patch QKV GEMM (M=32768,K=192,N=576) via bf16x3-split MFMA.
//        LDS-free: A loaded as f32 direct from x, hi/lo split in-register;
//        B from prepped global (L2-resident). 3-pass independent MFMAs.
//        Writes q-plane and w=(k+bk)(v+bv) plane (pixel layout) to d_ws.
// attn : out = q * sum fr(di,pi)*fc(dj,pj) * w_shifted, LDS-tiled 64x64+8halo.

#define HW 512
#define PLANE 6291456   // 8*3*512*512 elements per plane

typedef __attribute__((ext_vector_type(8))) short bf16x8;
typedef __attribute__((ext_vector_type(4))) float f32x4;

static __device__ __forceinline__ unsigned short bf16_rne(float f) {
    unsigned u = __builtin_bit_cast(unsigned, f);
    u += 0x7FFFu + ((u >> 16) & 1u);
    return (unsigned short)(u >> 16);
}
static __device__ __forceinline__ float bf16f(unsigned short h) {
    unsigned u = ((unsigned)h) << 16;
    return __builtin_bit_cast(float, u);
}

// ---------- prep: W -> fragment-major bf16 hi/lo (R5-verified) ----------
// Ws[ckt][half][kg 0..7][er 0..191][8 ushorts]; er = slot*64+dl (channel c of ckt)
__global__ void __launch_bounds__(256) wprep_kernel(const float* __restrict__ W,
                                                    unsigned short* __restrict__ Ws)
{
    int gid = blockIdx.x * 256 + threadIdx.x;      // 13824 = 54*256 exact
    int er  = gid % 192;
    int t   = gid / 192;
    int kg  = t & 7;
    int ckt = t >> 3;                              // c*3 + kt, 0..8
    int c = ckt / 3, kt = ckt % 3;
    int slot = er >> 6, dl = er & 63;
    const float* src = W + (size_t)(slot*192 + c*64 + dl)*192 + kt*64 + kg*8;
    float4 a = ((const float4*)src)[0], b = ((const float4*)src)[1];
    float v[8] = {a.x, a.y, a.z, a.w, b.x, b.y, b.z, b.w};
    unsigned short h[8], lo[8];
    #pragma unroll
    for (int u = 0; u < 8; ++u) {
        h[u]  = bf16_rne(v[u]);
        lo[u] = bf16_rne(v[u] - bf16f(h[u]));
    }
    uint4 hp, lp;
    hp.x = (unsigned)h[0] | ((unsigned)h[1] << 16);
    hp.y = (unsigned)h[2] | ((unsigned)h[3] << 16);
    hp.z = (unsigned)h[4] | ((unsigned)h[5] << 16);
    hp.w = (unsigned)h[6] | ((unsigned)h[7] << 16);
    lp.x = (unsigned)lo[0] | ((unsigned)lo[1] << 16);
    lp.y = (unsigned)lo[2] | ((unsigned)lo[3] << 16);
    lp.z = (unsigned)lo[4] | ((unsigned)lo[5] << 16);
    lp.w = (unsigned)lo[6] | ((unsigned)lo[7] << 16);
    size_t oh = ((size_t)((ckt*2 + 0)*8 + kg)*192 + er) * 8;
    size_t ol = ((size_t)((ckt*2 + 1)*8 + kg)*192 + er) * 8;
    *(uint4*)(Ws + oh) = hp;
    *(uint4*)(Ws + ol) = lp;
}

// ---------- qkv: LDS-free MFMA GEMM, in-register A split ----------
// grid (512, 3): blockIdx.x = b*64+i (tile-row), blockIdx.y = c (channel).
// 4 waves; wave wv owns dl in [wv*16, wv*16+16); n=0,1,2 selects slot q,k,v.
__global__ void __launch_bounds__(256) qkv_mfma_kernel(
    const float* __restrict__ x,
    const unsigned short* __restrict__ Ws,
    const float* __restrict__ bqkv,
    float* __restrict__ ws)
{
    const int tid = threadIdx.x;
    const int mb  = blockIdx.x;
    const int c   = blockIdx.y;
    const int b   = mb >> 6, i = mb & 63;
    const int wv  = tid >> 6;
    const int l   = tid & 63;
    const int lr  = l & 15;
    const int lk  = l >> 4;

    f32x4 acc[4][3];
    #pragma unroll
    for (int m = 0; m < 4; ++m)
        #pragma unroll
        for (int n = 0; n < 3; ++n)
            #pragma unroll
            for (int r = 0; r < 4; ++r) acc[m][n][r] = 0.f;

    #pragma unroll
    for (int kt = 0; kt < 3; ++kt) {
        const float* xp = x + ((size_t)(b*3 + kt)*HW + (size_t)i*8) * HW;
        const unsigned short* Bb = Ws + (size_t)(c*3 + kt) * 2 * 8 * 192 * 8;
        #pragma unroll
        for (int ks = 0; ks < 2; ++ks) {
            const int pi = ks*4 + lk;                 // k-octet = pixel row pi
            // ---- A: load 8 f32 direct, split hi/lo in-register ----
            bf16x8 ah[4], al[4];
            #pragma unroll
            for (int m = 0; m < 4; ++m) {
                int j = m*16 + lr;
                const float* ap = xp + (size_t)pi*HW + j*8;
                float4 a0 = *(const float4*)ap;
                float4 a1 = *(const float4*)(ap + 4);
                float v[8] = {a0.x, a0.y, a0.z, a0.w, a1.x, a1.y, a1.z, a1.w};
                #pragma unroll
                for (int u = 0; u < 8; ++u) {
                    unsigned short h = bf16_rne(v[u]);
                    ah[m][u] = (short)h;
                    al[m][u] = (short)bf16_rne(v[u] - bf16f(h));
                }
            }
            // ---- B: prepped fragments (L2-resident) ----
            bf16x8 bh[3], bl[3];
            #pragma unroll
            for (int n = 0; n < 3; ++n) {
                int er = n*64 + wv*16 + lr;
                size_t oh = ((size_t)(0*8 + ks*4 + lk)*192 + er) * 8;
                size_t ol = ((size_t)(1*8 + ks*4 + lk)*192 + er) * 8;
                bh[n] = *(const bf16x8*)(Bb + oh);
                bl[n] = *(const bf16x8*)(Bb + ol);
            }
            // ---- 3 passes of 12 independent MFMAs ----
            #pragma unroll
            for (int m = 0; m < 4; ++m)
                #pragma unroll
                for (int n = 0; n < 3; ++n)
                    acc[m][n] = __builtin_amdgcn_mfma_f32_16x16x32_bf16(al[m], bh[n], acc[m][n], 0, 0, 0);
            #pragma unroll
            for (int m = 0; m < 4; ++m)
                #pragma unroll
                for (int n = 0; n < 3; ++n)
                    acc[m][n] = __builtin_amdgcn_mfma_f32_16x16x32_bf16(ah[m], bl[n], acc[m][n], 0, 0, 0);
            #pragma unroll
            for (int m = 0; m < 4; ++m)
                #pragma unroll
                for (int n = 0; n < 3; ++n)
                    acc[m][n] = __builtin_amdgcn_mfma_f32_16x16x32_bf16(ah[m], bh[n], acc[m][n], 0, 0, 0);
        }
    }

    // ---- epilogue: in-register w = (k+bk)(v+bv); direct dword stores ----
    const int dl = wv*16 + lr;
    const float bq = bqkv[      c*64 + dl];
    const float bk = bqkv[192 + c*64 + dl];
    const float bv = bqkv[384 + c*64 + dl];
    const int ppi = dl >> 3, ppj = dl & 7;
    float* qplane = ws;
    float* wplane = ws + PLANE;
    size_t rowoff = ((size_t)(b*3 + c)*HW + (size_t)(i*8 + ppi))*HW + ppj;
    #pragma unroll
    for (int m = 0; m < 4; ++m)
        #pragma unroll
        for (int ri = 0; ri < 4; ++ri) {
            int j = m*16 + lk*4 + ri;               // D row = (l>>4)*4 + reg
            float qv  = acc[m][0][ri] + bq;
            float wvv = (acc[m][1][ri] + bk) * (acc[m][2][ri] + bv);
            qplane[rowoff + (size_t)j*8] = qv;
            wplane[rowoff + (size_t)j*8] = wvv;
        }
}

// ---------- attn: LDS-tiled 9-tap stencil (R5-verified) ----------
__global__ void __launch_bounds__(256) attn_kernel(
    const float* __restrict__ ws,
    const float* __restrict__ bqkv,
    float* __restrict__ out)
{
    __shared__ float wt[80][84];
    const int tid = threadIdx.x;
    int bid = blockIdx.x;
    int txt = (bid & 7) << 6;
    int tyt = ((bid >> 3) & 7) << 6;
    int pl  = bid >> 6;                           // b*3 + c
    int c   = pl % 3;
    const float* qplane = ws + (size_t)pl * (HW*HW);
    const float* wplane = ws + PLANE + (size_t)pl * (HW*HW);

    const int pi  = (tid >> 4) & 7;
    const int pj0 = (tid & 1) << 2;
    const float fr0 = __expf((float)(pi - 7) * 0.25f);
    const float fr2 = __expf((float)(-pi) * 0.25f);
    float fa[4], fb[4];
    #pragma unroll
    for (int u = 0; u < 4; ++u) {
        int pj = pj0 + u;
        fa[u] = __expf((float)(pj - 7) * 0.25f);
        fb[u] = __expf((float)(-pj) * 0.25f);
    }

    for (int it = 0; it < 7; ++it) {
        int f = tid + it*256;
        if (f < 1600) {                           // 80 rows x 20 float4
            int r  = f / 20;
            int c4 = f - r*20;
            int gy = tyt - 8 + r;
            int gx = txt - 8 + (c4 << 2);
            float4 v;
            if ((unsigned)gy < 512u && (unsigned)gx < 512u) {
                v = *(const float4*)(wplane + (size_t)gy*HW + gx);
            } else {
                int d0 = c*64 + (gy & 7)*8 + (gx & 7);
                float4 bk = *(const float4*)(bqkv + 192 + d0);
                float4 bv = *(const float4*)(bqkv + 384 + d0);
                v.x = bk.x*bv.x; v.y = bk.y*bv.y; v.z = bk.z*bv.z; v.w = bk.w*bv.w;
            }
            *(float4*)&wt[r][c4 << 2] = v;
        }
    }
    __syncthreads();

    #pragma unroll
    for (int it = 0; it < 4; ++it) {
        int f  = tid + it*256;
        int ly = f >> 4;
        int lx = (f & 15) << 2;
        float sx = 0.f, sy = 0.f, sz = 0.f, sw = 0.f;
        #pragma unroll
        for (int di = 0; di < 3; ++di) {
            const float* row = &wt[ly + 8*di][lx];
            float4 w0 = *(const float4*)(row);
            float4 w1 = *(const float4*)(row + 8);
            float4 w2 = *(const float4*)(row + 16);
            float fr = (di == 0) ? fr0 : (di == 1) ? 1.f : fr2;
            sx += fr * (fa[0]*w0.x + w1.x + fb[0]*w2.x);
            sy += fr * (fa[1]*w0.y + w1.y + fb[1]*w2.y);
            sz += fr * (fa[2]*w0.z + w1.z + fb[2]*w2.z);
            sw += fr * (fa[3]*w0.w + w1.w + fb[3]*w2.w);
        }
        size_t off = (size_t)pl*(HW*HW) + (size_t)(tyt + ly)*HW + txt + lx;
        float4 q4 = *(const float4*)(qplane + (size_t)(tyt + ly)*HW + txt + lx);
        float4 o;
        o.x = q4.x*sx; o.y = q4.y*sy; o.z = q4.z*sz; o.w = q4.w*sw;
        *(float4*)(out + off) = o;
    }
}

extern "C" void kernel_launch(void* const* d_in, const int* in_sizes, int n_in,
                              void* d_out, int out_size, void* d_ws, size_t ws_size,
                              hipStream_t stream)
{
    const float* x  = (const float*)d_in[0];   // [8][3][512][512]
    const float* W  = (const float*)d_in[1];   // [576][192]
    const float* bq = (const float*)d_in[2];   // [576]
    float* wsf = (float*)d_ws;                 // q-plane f32 | w-plane f32 | Wsplit
    unsigned short* Wsplit = (unsigned short*)(wsf + 2*(size_t)PLANE);

    wprep_kernel<<<54, 256, 0, stream>>>(W, Wsplit);
    qkv_mfma_kernel<<<dim3(512, 3), 256, 0, stream>>>(x, Wsplit, bq, wsf);
    attn_kernel<<<1536, 256, 0, stream>>>(wsf, bq, (float*)d_out);
}

// Round 11
// 115.723 us; speedup vs baseline: 1.2856x; 1.0583x over previous
//
#include <hip/hip_runtime.h>
#include <hip/hip_fp16.h>

// AttentionConv on MI355X (gfx950) — split design.
// wprep: W -> bf16 hi/lo (RNE), fragment-major (lane-coalesced).
// qkv  : per-patch QKV GEMM (M=32768,K=192,N=576) via bf16x3-split MFMA.
//        LDS-free. A loaded f32 direct from x; TRUNCATION hi/lo split packed
//        with v_perm_b32 (3 VALU/elem). Writes q and w=(k+bk)(v+bv) as FP16
//        planes (pixel layout) to d_ws.
// attn : out = q * sum fr(di,pi)*fc(dj,pj) * w_shifted, LDS-tiled 64x64+8halo,
//        fp16 plane reads, f32 stencil math, f32 out.

#define HW 512
#define PLANE 6291456   // 8*3*512*512 elements per plane

typedef __attribute__((ext_vector_type(8))) short bf16x8;
typedef __attribute__((ext_vector_type(4))) float f32x4;
typedef __attribute__((ext_vector_type(4))) unsigned int u32x4;

static __device__ __forceinline__ unsigned short bf16_rne(float f) {
    unsigned u = __builtin_bit_cast(unsigned, f);
    u += 0x7FFFu + ((u >> 16) & 1u);
    return (unsigned short)(u >> 16);
}
static __device__ __forceinline__ float bf16f(unsigned short h) {
    unsigned u = ((unsigned)h) << 16;
    return __builtin_bit_cast(float, u);
}
static __device__ __forceinline__ float ubits_f(unsigned u) {
    return __builtin_bit_cast(float, u);
}
static __device__ __forceinline__ unsigned f_ubits(float f) {
    return __builtin_bit_cast(unsigned, f);
}

// ---------- prep: W -> fragment-major bf16 hi/lo (verified) ----------
// Ws[ckt][half][kg 0..7][er 0..191][8 ushorts]; er = slot*64+dl (channel c of ckt)
__global__ void __launch_bounds__(256) wprep_kernel(const float* __restrict__ W,
                                                    unsigned short* __restrict__ Ws)
{
    int gid = blockIdx.x * 256 + threadIdx.x;      // 13824 = 54*256 exact
    int er  = gid % 192;
    int t   = gid / 192;
    int kg  = t & 7;
    int ckt = t >> 3;                              // c*3 + kt, 0..8
    int c = ckt / 3, kt = ckt % 3;
    int slot = er >> 6, dl = er & 63;
    const float* src = W + (size_t)(slot*192 + c*64 + dl)*192 + kt*64 + kg*8;
    float4 a = ((const float4*)src)[0], b = ((const float4*)src)[1];
    float v[8] = {a.x, a.y, a.z, a.w, b.x, b.y, b.z, b.w};
    unsigned short h[8], lo[8];
    #pragma unroll
    for (int u = 0; u < 8; ++u) {
        h[u]  = bf16_rne(v[u]);
        lo[u] = bf16_rne(v[u] - bf16f(h[u]));
    }
    uint4 hp, lp;
    hp.x = (unsigned)h[0] | ((unsigned)h[1] << 16);
    hp.y = (unsigned)h[2] | ((unsigned)h[3] << 16);
    hp.z = (unsigned)h[4] | ((unsigned)h[5] << 16);
    hp.w = (unsigned)h[6] | ((unsigned)h[7] << 16);
    lp.x = (unsigned)lo[0] | ((unsigned)lo[1] << 16);
    lp.y = (unsigned)lo[2] | ((unsigned)lo[3] << 16);
    lp.z = (unsigned)lo[4] | ((unsigned)lo[5] << 16);
    lp.w = (unsigned)lo[6] | ((unsigned)lo[7] << 16);
    size_t oh = ((size_t)((ckt*2 + 0)*8 + kg)*192 + er) * 8;
    size_t ol = ((size_t)((ckt*2 + 1)*8 + kg)*192 + er) * 8;
    *(uint4*)(Ws + oh) = hp;
    *(uint4*)(Ws + ol) = lp;
}

// ---------- qkv: LDS-free MFMA GEMM, trunc-split A, fp16 outputs ----------
// grid (512, 3): blockIdx.x = b*64+i (tile-row), blockIdx.y = c (channel).
// 4 waves; wave wv owns dl in [wv*16, wv*16+16); n=0,1,2 selects slot q,k,v.
__global__ void __launch_bounds__(256) qkv_mfma_kernel(
    const float* __restrict__ x,
    const unsigned short* __restrict__ Ws,
    const float* __restrict__ bqkv,
    __half* __restrict__ ws)
{
    const int tid = threadIdx.x;
    const int mb  = blockIdx.x;
    const int c   = blockIdx.y;
    const int b   = mb >> 6, i = mb & 63;
    const int wv  = tid >> 6;
    const int l   = tid & 63;
    const int lr  = l & 15;
    const int lk  = l >> 4;

    f32x4 acc[4][3];
    #pragma unroll
    for (int m = 0; m < 4; ++m)
        #pragma unroll
        for (int n = 0; n < 3; ++n)
            #pragma unroll
            for (int r = 0; r < 4; ++r) acc[m][n][r] = 0.f;

    #pragma unroll
    for (int kt = 0; kt < 3; ++kt) {
        const float* xp = x + ((size_t)(b*3 + kt)*HW + (size_t)i*8) * HW;
        const unsigned short* Bb = Ws + (size_t)(c*3 + kt) * 2 * 8 * 192 * 8;
        #pragma unroll
        for (int ks = 0; ks < 2; ++ks) {
            const int pi = ks*4 + lk;                 // k-octet = pixel row pi
            // ---- A: load 8 f32, TRUNC hi/lo split, v_perm pack ----
            bf16x8 ah[4], al[4];
            #pragma unroll
            for (int m = 0; m < 4; ++m) {
                int j = m*16 + lr;
                const float* ap = xp + (size_t)pi*HW + j*8;
                uint4 a0 = *(const uint4*)ap;         // bits of 4 f32
                uint4 a1 = *(const uint4*)(ap + 4);
                // hi = top16 bits (trunc bf16); pack pairs (even->low short)
                unsigned h01 = __builtin_amdgcn_perm(a0.y, a0.x, 0x07060302u);
                unsigned h23 = __builtin_amdgcn_perm(a0.w, a0.z, 0x07060302u);
                unsigned h45 = __builtin_amdgcn_perm(a1.y, a1.x, 0x07060302u);
                unsigned h67 = __builtin_amdgcn_perm(a1.w, a1.z, 0x07060302u);
                // l = x - hi (exact); lo = top16 bits of l
                unsigned l0 = f_ubits(ubits_f(a0.x) - ubits_f(a0.x & 0xFFFF0000u));
                unsigned l1 = f_ubits(ubits_f(a0.y) - ubits_f(a0.y & 0xFFFF0000u));
                unsigned l2 = f_ubits(ubits_f(a0.z) - ubits_f(a0.z & 0xFFFF0000u));
                unsigned l3 = f_ubits(ubits_f(a0.w) - ubits_f(a0.w & 0xFFFF0000u));
                unsigned l4 = f_ubits(ubits_f(a1.x) - ubits_f(a1.x & 0xFFFF0000u));
                unsigned l5 = f_ubits(ubits_f(a1.y) - ubits_f(a1.y & 0xFFFF0000u));
                unsigned l6 = f_ubits(ubits_f(a1.z) - ubits_f(a1.z & 0xFFFF0000u));
                unsigned l7 = f_ubits(ubits_f(a1.w) - ubits_f(a1.w & 0xFFFF0000u));
                unsigned q01 = __builtin_amdgcn_perm(l1, l0, 0x07060302u);
                unsigned q23 = __builtin_amdgcn_perm(l3, l2, 0x07060302u);
                unsigned q45 = __builtin_amdgcn_perm(l5, l4, 0x07060302u);
                unsigned q67 = __builtin_amdgcn_perm(l7, l6, 0x07060302u);
                u32x4 hv = {h01, h23, h45, h67};
                u32x4 lv = {q01, q23, q45, q67};
                ah[m] = __builtin_bit_cast(bf16x8, hv);
                al[m] = __builtin_bit_cast(bf16x8, lv);
            }
            // ---- B: prepped fragments (L2-resident) ----
            bf16x8 bh[3], bl[3];
            #pragma unroll
            for (int n = 0; n < 3; ++n) {
                int er = n*64 + wv*16 + lr;
                size_t oh = ((size_t)(0*8 + ks*4 + lk)*192 + er) * 8;
                size_t ol = ((size_t)(1*8 + ks*4 + lk)*192 + er) * 8;
                bh[n] = *(const bf16x8*)(Bb + oh);
                bl[n] = *(const bf16x8*)(Bb + ol);
            }
            // ---- 3 passes of 12 independent MFMAs ----
            #pragma unroll
            for (int m = 0; m < 4; ++m)
                #pragma unroll
                for (int n = 0; n < 3; ++n)
                    acc[m][n] = __builtin_amdgcn_mfma_f32_16x16x32_bf16(al[m], bh[n], acc[m][n], 0, 0, 0);
            #pragma unroll
            for (int m = 0; m < 4; ++m)
                #pragma unroll
                for (int n = 0; n < 3; ++n)
                    acc[m][n] = __builtin_amdgcn_mfma_f32_16x16x32_bf16(ah[m], bl[n], acc[m][n], 0, 0, 0);
            #pragma unroll
            for (int m = 0; m < 4; ++m)
                #pragma unroll
                for (int n = 0; n < 3; ++n)
                    acc[m][n] = __builtin_amdgcn_mfma_f32_16x16x32_bf16(ah[m], bh[n], acc[m][n], 0, 0, 0);
        }
    }

    // ---- epilogue: w = (k+bk)(v+bv), q -> fp16 planes ----
    const int dl = wv*16 + lr;
    const float bq = bqkv[      c*64 + dl];
    const float bk = bqkv[192 + c*64 + dl];
    const float bv = bqkv[384 + c*64 + dl];
    const int ppi = dl >> 3, ppj = dl & 7;
    __half* qplane = ws;
    __half* wplane = ws + PLANE;
    size_t rowoff = ((size_t)(b*3 + c)*HW + (size_t)(i*8 + ppi))*HW + ppj;
    #pragma unroll
    for (int m = 0; m < 4; ++m)
        #pragma unroll
        for (int ri = 0; ri < 4; ++ri) {
            int j = m*16 + lk*4 + ri;               // D row = (l>>4)*4 + reg
            float qv  = acc[m][0][ri] + bq;
            float wvv = (acc[m][1][ri] + bk) * (acc[m][2][ri] + bv);
            qplane[rowoff + (size_t)j*8] = __float2half_rn(qv);
            wplane[rowoff + (size_t)j*8] = __float2half_rn(wvv);
        }
}

// ---------- attn: LDS-tiled 9-tap stencil, fp16 plane reads ----------
__global__ void __launch_bounds__(256) attn_kernel(
    const __half* __restrict__ ws,
    const float* __restrict__ bqkv,
    float* __restrict__ out)
{
    __shared__ float wt[80][84];
    const int tid = threadIdx.x;
    int bid = blockIdx.x;
    int txt = (bid & 7) << 6;
    int tyt = ((bid >> 3) & 7) << 6;
    int pl  = bid >> 6;                           // b*3 + c
    int c   = pl % 3;
    const __half* qplane = ws + (size_t)pl * (HW*HW);
    const __half* wplane = ws + PLANE + (size_t)pl * (HW*HW);

    const int pi  = (tid >> 4) & 7;
    const int pj0 = (tid & 1) << 2;
    const float fr0 = __expf((float)(pi - 7) * 0.25f);
    const float fr2 = __expf((float)(-pi) * 0.25f);
    float fa[4], fb[4];
    #pragma unroll
    for (int u = 0; u < 4; ++u) {
        int pj = pj0 + u;
        fa[u] = __expf((float)(pj - 7) * 0.25f);
        fb[u] = __expf((float)(-pj) * 0.25f);
    }

    // stage 80x80 fp16 w-halo -> f32 LDS (8 halves per slot)
    #pragma unroll
    for (int it = 0; it < 4; ++it) {
        int f = tid + it*256;
        if (f < 800) {                            // 80 rows x 10 half8
            int r  = f / 10;
            int c8 = f - r*10;
            int gy = tyt - 8 + r;
            int gx = txt - 8 + c8*8;
            float o[8];
            if ((unsigned)gy < 512u && (unsigned)gx < 512u) {
                uint4 hv = *(const uint4*)(wplane + (size_t)gy*HW + gx);
                const __half2* hp = (const __half2*)&hv;
                #pragma unroll
                for (int t = 0; t < 4; ++t) {
                    float2 f2 = __half22float2(hp[t]);
                    o[2*t] = f2.x; o[2*t+1] = f2.y;
                }
            } else {
                int d0 = c*64 + (gy & 7)*8;       // gx%8==0 here
                float4 k0 = *(const float4*)(bqkv + 192 + d0);
                float4 k1 = *(const float4*)(bqkv + 196 + d0);
                float4 v0 = *(const float4*)(bqkv + 384 + d0);
                float4 v1 = *(const float4*)(bqkv + 388 + d0);
                o[0]=k0.x*v0.x; o[1]=k0.y*v0.y; o[2]=k0.z*v0.z; o[3]=k0.w*v0.w;
                o[4]=k1.x*v1.x; o[5]=k1.y*v1.y; o[6]=k1.z*v1.z; o[7]=k1.w*v1.w;
            }
            float* dst = &wt[r][c8*8];
            *(float4*)dst       = make_float4(o[0], o[1], o[2], o[3]);
            *(float4*)(dst + 4) = make_float4(o[4], o[5], o[6], o[7]);
        }
    }
    __syncthreads();

    #pragma unroll
    for (int it = 0; it < 4; ++it) {
        int f  = tid + it*256;
        int ly = f >> 4;
        int lx = (f & 15) << 2;
        float sx = 0.f, sy = 0.f, sz = 0.f, sw = 0.f;
        #pragma unroll
        for (int di = 0; di < 3; ++di) {
            const float* row = &wt[ly + 8*di][lx];
            float4 w0 = *(const float4*)(row);
            float4 w1 = *(const float4*)(row + 8);
            float4 w2 = *(const float4*)(row + 16);
            float fr = (di == 0) ? fr0 : (di == 1) ? 1.f : fr2;
            sx += fr * (fa[0]*w0.x + w1.x + fb[0]*w2.x);
            sy += fr * (fa[1]*w0.y + w1.y + fb[1]*w2.y);
            sz += fr * (fa[2]*w0.z + w1.z + fb[2]*w2.z);
            sw += fr * (fa[3]*w0.w + w1.w + fb[3]*w2.w);
        }
        const __half* qp = qplane + (size_t)(tyt + ly)*HW + txt + lx;
        float2 q01 = __half22float2(*(const __half2*)qp);
        float2 q23 = __half22float2(*(const __half2*)(qp + 2));
        size_t off = (size_t)pl*(HW*HW) + (size_t)(tyt + ly)*HW + txt + lx;
        float4 o;
        o.x = q01.x*sx; o.y = q01.y*sy; o.z = q23.x*sz; o.w = q23.y*sw;
        *(float4*)(out + off) = o;
    }
}

extern "C" void kernel_launch(void* const* d_in, const int* in_sizes, int n_in,
                              void* d_out, int out_size, void* d_ws, size_t ws_size,
                              hipStream_t stream)
{
    const float* x  = (const float*)d_in[0];   // [8][3][512][512]
    const float* W  = (const float*)d_in[1];   // [576][192]
    const float* bq = (const float*)d_in[2];   // [576]
    __half* wsh = (__half*)d_ws;               // q fp16 | w fp16 | Wsplit
    unsigned short* Wsplit = (unsigned short*)(wsh + 2*(size_t)PLANE);

    wprep_kernel<<<54, 256, 0, stream>>>(W, Wsplit);
    qkv_mfma_kernel<<<dim3(512, 3), 256, 0, stream>>>(x, Wsplit, bq, wsh);
    attn_kernel<<<1536, 256, 0, stream>>>(wsh, bq, (float*)d_out);
}